// Round 3
// baseline (283.204 us; speedup 1.0000x reference)
//
#include <hip/hip_runtime.h>
#include <cstdint>

typedef unsigned short u16;
typedef __attribute__((ext_vector_type(8))) __bf16 bf16x8;
typedef __attribute__((ext_vector_type(4))) float f32x4;
typedef __attribute__((ext_vector_type(8))) unsigned short u16x8;

#define DEV __device__ __forceinline__

DEV u16 f2bf(float f) {
  __bf16 b = (__bf16)f;
  return __builtin_bit_cast(u16, b);
}
DEV float bf2f(u16 h) { return __uint_as_float(((unsigned)h) << 16); }
DEV float exp2_fast(float x) { float r; asm("v_exp_f32 %0, %1" : "=v"(r) : "v"(x)); return r; }

typedef __attribute__((address_space(1))) void gvoid_t;
typedef __attribute__((address_space(3))) void lvoid_t;

DEV void gload_lds16(const void* g, void* l) {
  __builtin_amdgcn_global_load_lds((gvoid_t*)(void*)(uintptr_t)g,
                                   (lvoid_t*)l, 16, 0, 0);
}

// ---- problem sizes
#define B_   2
#define T_   2048
#define DM   2048
#define MROWS (B_*T_)   // 4096

// ---------- x f32 -> bf16 ----------
__global__ void k_convert(const float* __restrict__ in, u16* __restrict__ out, int n4) {
  int i = blockIdx.x * blockDim.x + threadIdx.x;
  if (i >= n4) return;
  float4 v = ((const float4*)in)[i];
  ((ushort4*)out)[i] = make_ushort4(f2bf(v.x), f2bf(v.y), f2bf(v.z), f2bf(v.w));
}

// ---------- weight f32 [R][C] -> bf16 [C][R] ----------
__global__ void k_transpose(const float* __restrict__ in, u16* __restrict__ out, int R, int C) {
  __shared__ float tile[32][33];
  int c0 = blockIdx.x * 32, r0 = blockIdx.y * 32;
  int tx = threadIdx.x, ty = threadIdx.y;   // (32, 8)
  #pragma unroll
  for (int j = 0; j < 32; j += 8)
    tile[ty + j][tx] = in[(size_t)(r0 + ty + j) * C + c0 + tx];
  __syncthreads();
  #pragma unroll
  for (int j = 0; j < 32; j += 8)
    out[(size_t)(c0 + ty + j) * R + r0 + tx] = f2bf(tile[tx][ty + j]);
}

// ---------- RoPE cos/sin table [T][64] ----------
__global__ void k_rope_table(float2* __restrict__ tab) {
  int i = blockIdx.x * blockDim.x + threadIdx.x;   // < 2048*64
  int pos = i >> 6, d = i & 63;
  float ang = powf(10000.0f, -(float)d / 64.0f);
  float s, c;
  sincosf((float)pos * ang, &s, &c);
  tab[i] = make_float2(c, s);
}

// ---------- bf16 GEMM: C[M][N] = A[M][K] * BT[N][K]^T ----------
template <typename OutT>
__global__ __launch_bounds__(256) void k_gemm(
    const u16* __restrict__ A, const u16* __restrict__ BT, OutT* __restrict__ C,
    int M, int N, int K) {
  __shared__ u16 As[128 * 64];
  __shared__ u16 Bs[128 * 64];
  const int tid = threadIdx.x;
  const int w = tid >> 6, lane = tid & 63;
  const int lr = lane & 15, lg = lane >> 4;
  const int m0 = blockIdx.y * 128, n0 = blockIdx.x * 128;
  const int wr = w >> 1, wc = w & 1;
  f32x4 acc[4][4] = {};
  for (int k0 = 0; k0 < K; k0 += 64) {
    __syncthreads();
    #pragma unroll
    for (int i = 0; i < 4; i++) {
      int idx = i * 256 + tid;            // 0..1023
      int row = idx >> 3, blk = idx & 7;  // 8x16B blocks per 128B row
      int scol = ((blk ^ (row & 7)) << 3);
      gload_lds16(&A[(size_t)(m0 + row) * K + k0 + scol], &As[(idx & ~63) * 8]);
      gload_lds16(&BT[(size_t)(n0 + row) * K + k0 + scol], &Bs[(idx & ~63) * 8]);
    }
    __syncthreads();
    #pragma unroll
    for (int kk = 0; kk < 2; kk++) {
      bf16x8 af[4], bfr[4];
      #pragma unroll
      for (int m = 0; m < 4; m++) {
        int row = wr * 64 + m * 16 + lr;
        af[m] = *(const bf16x8*)&As[row * 64 + (((kk * 4 + lg) ^ (lr & 7)) << 3)];
      }
      #pragma unroll
      for (int n = 0; n < 4; n++) {
        int row = wc * 64 + n * 16 + lr;
        bfr[n] = *(const bf16x8*)&Bs[row * 64 + (((kk * 4 + lg) ^ (lr & 7)) << 3)];
      }
      #pragma unroll
      for (int m = 0; m < 4; m++)
        #pragma unroll
        for (int n = 0; n < 4; n++)
          acc[m][n] = __builtin_amdgcn_mfma_f32_16x16x32_bf16(af[m], bfr[n], acc[m][n], 0, 0, 0);
    }
  }
  #pragma unroll
  for (int m = 0; m < 4; m++)
    #pragma unroll
    for (int n = 0; n < 4; n++)
      #pragma unroll
      for (int r = 0; r < 4; r++) {
        int row = m0 + wr * 64 + m * 16 + lg * 4 + r;
        int col = n0 + wc * 64 + n * 16 + lr;
        if constexpr (sizeof(OutT) == 2) C[(size_t)row * N + col] = f2bf(acc[m][n][r]);
        else                             C[(size_t)row * N + col] = acc[m][n][r];
      }
}

// ---------- Q: RMSNorm * gq, RoPE, * (D^-0.5 * log2e) ; qkv [bt][3072] -> [b,g,h,t,d] ----------
__global__ void k_norm_rope_q(const u16* __restrict__ qkvf, const float* __restrict__ gq,
                              const float2* __restrict__ tab, u16* __restrict__ qb) {
  int w = threadIdx.x >> 6, lane = threadIdx.x & 63;
  int W = blockIdx.x * 4 + w;               // 0..65535
  int h = W & 3, g = (W >> 2) & 3;
  int bt = W >> 4;
  int t = bt & 2047, b = bt >> 11;
  const u16* row = qkvf + (size_t)bt * 3072 + (size_t)(g * 4 + h) * 128;
  float v0 = bf2f(row[lane]);
  float v1 = bf2f(row[lane + 64]);
  float ss = v0 * v0 + v1 * v1;
  #pragma unroll
  for (int off = 1; off < 64; off <<= 1) ss += __shfl_xor(ss, off, 64);
  float inv = 1.0f / sqrtf(ss * (1.0f / 128.0f) + 1e-6f);
  v0 *= inv * gq[(g * 4 + h) * 128 + lane];
  v1 *= inv * gq[(g * 4 + h) * 128 + 64 + lane];
  float2 cs = tab[t * 64 + lane];
  const float sc = 0.1275174f;    // 128^-0.5 * log2(e), both mult factors folded into q
  float o0 = (v0 * cs.x - v1 * cs.y) * sc;
  float o1 = (v0 * cs.y + v1 * cs.x) * sc;
  u16* orow = qb + ((size_t)(((b * 4 + g) * 4 + h) * 2048 + t)) * 128;
  orow[lane] = f2bf(o0);
  orow[lane + 64] = f2bf(o1);
}

// ---------- K: RMSNorm * gk, RoPE ; qkv [bt][3072] cols 2048..2559 -> [b,g,t,d] ----------
__global__ void k_norm_rope_k(const u16* __restrict__ qkvf, const float* __restrict__ gk,
                              const float2* __restrict__ tab, u16* __restrict__ kb) {
  int w = threadIdx.x >> 6, lane = threadIdx.x & 63;
  int W = blockIdx.x * 4 + w;               // 0..16383
  int g = W & 3;
  int bt = W >> 2;
  int t = bt & 2047, b = bt >> 11;
  const u16* row = qkvf + (size_t)bt * 3072 + 2048 + (size_t)g * 128;
  float v0 = bf2f(row[lane]);
  float v1 = bf2f(row[lane + 64]);
  float ss = v0 * v0 + v1 * v1;
  #pragma unroll
  for (int off = 1; off < 64; off <<= 1) ss += __shfl_xor(ss, off, 64);
  float inv = 1.0f / sqrtf(ss * (1.0f / 128.0f) + 1e-6f);
  v0 *= inv * gk[g * 128 + lane];
  v1 *= inv * gk[g * 128 + 64 + lane];
  float2 cs = tab[t * 64 + lane];
  float o0 = v0 * cs.x - v1 * cs.y;
  float o1 = v0 * cs.y + v1 * cs.x;
  u16* orow = kb + ((size_t)((b * 4 + g) * 2048 + t)) * 128;
  orow[lane] = f2bf(o0);
  orow[lane + 64] = f2bf(o1);
}

// ---------- V: qkv [bt][3072] cols 2560..3071 -> VT [b,g,d,t] ----------
__global__ void k_pack_vt(const u16* __restrict__ qkvf, u16* __restrict__ vt) {
  int w = threadIdx.x >> 6, lane = threadIdx.x & 63;
  int W = blockIdx.x * 4 + w;               // 0..4095
  int t8 = W & 255, dh = (W >> 8) & 1, bg = W >> 9;
  int b = bg >> 2, g = bg & 3;
  int t0 = t8 * 8;
  int d = dh * 64 + lane;
  u16x8 pack;
  #pragma unroll
  for (int j = 0; j < 8; j++)
    pack[j] = qkvf[(size_t)(b * 2048 + t0 + j) * 3072 + 2560 + g * 128 + d];
  *(u16x8*)&vt[((size_t)(bg * 128 + d)) * 2048 + t0] = pack;
}

// ---------- staging: K tile [64][128] + VT tile [128][64], pre-swizzled source ----------
DEV void stage_tiles(const u16* kh, const u16* vh, int j0, u16* Kbuf, u16* Vbuf, int tid) {
  #pragma unroll
  for (int i = 0; i < 4; i++) {
    int idx = i * 256 + tid;
    int row = idx >> 4, blk = idx & 15;   // 16x16B blocks per 256B K row
    gload_lds16(&kh[(size_t)(j0 + row) * 128 + ((blk ^ (row & 7)) << 3)],
                &Kbuf[(idx & ~63) * 8]);
  }
  #pragma unroll
  for (int i = 0; i < 4; i++) {
    int idx = i * 256 + tid;
    int row = idx >> 3, blk = idx & 7;    // 8x16B blocks per 128B VT row
    gload_lds16(&vh[(size_t)row * T_ + j0 + ((blk ^ (row & 7)) << 3)],
                &Vbuf[(idx & ~63) * 8]);
  }
}

// ---------- one q-tile's QK^T + online softmax (exp2 domain, defer-max) + PV ----------
DEV void attn_tile(const u16* __restrict__ Kc, const u16* __restrict__ Vc,
                   u16* __restrict__ Psw, const bf16x8* qf, f32x4* oacc,
                   float& mrun, float& lsum,
                   int lr, int lg, int w, bool diag) {
  // S^T = K . Q^T : col = q (lr), row = kv (c*16 + lg*4 + r)
  f32x4 s[4] = {};
  #pragma unroll
  for (int kk = 0; kk < 4; kk++) {
    #pragma unroll
    for (int c = 0; c < 4; c++) {
      const int kvr = c * 16 + lr;
      bf16x8 kf = *(const bf16x8*)&Kc[kvr * 128 + (((kk * 4 + lg) ^ (kvr & 7)) << 3)];
      s[c] = __builtin_amdgcn_mfma_f32_16x16x32_bf16(kf, qf[kk], s[c], 0, 0, 0);
    }
  }
  if (diag) {
    #pragma unroll
    for (int c = 0; c < 4; c++)
      #pragma unroll
      for (int r = 0; r < 4; r++)
        if (c * 16 + lg * 4 + r > w * 16 + lr) s[c][r] = -1.0e30f;
  }
  float mx = s[0][0];
  #pragma unroll
  for (int c = 0; c < 4; c++)
    #pragma unroll
    for (int r = 0; r < 4; r++) mx = fmaxf(mx, s[c][r]);
  mx = fmaxf(mx, __shfl_xor(mx, 16, 64));
  mx = fmaxf(mx, __shfl_xor(mx, 32, 64));
  // defer-max: only rescale when tile max grew past mrun + 11 (log2 units; P <= 2^11)
  if (!__all(mx <= mrun + 11.0f)) {
    float mnew = fmaxf(mrun, mx);
    float corr = exp2_fast(mrun - mnew);
    mrun = mnew;
    lsum *= corr;
    float cr[4];
    #pragma unroll
    for (int r = 0; r < 4; r++) cr[r] = __shfl(corr, lg * 4 + r, 64);
    #pragma unroll
    for (int nd = 0; nd < 8; nd++) {
      oacc[nd][0] *= cr[0]; oacc[nd][1] *= cr[1];
      oacc[nd][2] *= cr[2]; oacc[nd][3] *= cr[3];
    }
  }
  float rs = 0.f;
  #pragma unroll
  for (int c = 0; c < 4; c++)
    #pragma unroll
    for (int r = 0; r < 4; r++) {
      float pv = exp2_fast(s[c][r] - mrun);
      s[c][r] = pv;
      rs += pv;
    }
  lsum += rs;                 // per-lane partial; cross-lane reduce deferred to epilogue
  // P store: P[q=lr][kv quad c*16+lg*4], b64, XOR-swizzled 8B blocks
  #pragma unroll
  for (int c = 0; c < 4; c++) {
    ushort4 q4 = make_ushort4(f2bf(s[c][0]), f2bf(s[c][1]), f2bf(s[c][2]), f2bf(s[c][3]));
    int blk8 = (c * 4 + lg) ^ ((lr & 7) << 1);
    *(ushort4*)&Psw[lr * 64 + blk8 * 4] = q4;
  }
  // O += P V
  #pragma unroll
  for (int ks = 0; ks < 2; ks++) {
    bf16x8 pf = *(const bf16x8*)&Psw[lr * 64 +
                 (((2 * (ks * 4 + lg)) ^ ((lr & 7) << 1)) << 2)];
    #pragma unroll
    for (int nd = 0; nd < 8; nd++) {
      const int d = nd * 16 + lr;
      bf16x8 vf = *(const bf16x8*)&Vc[d * 64 + (((ks * 4 + lg) ^ (d & 7)) << 3)];
      oacc[nd] = __builtin_amdgcn_mfma_f32_16x16x32_bf16(pf, vf, oacc[nd], 0, 0, 0);
    }
  }
}

DEV void attn_epilogue(u16* __restrict__ ob, int b, int g, int h, int q0,
                       const f32x4* oacc, float lsum, int lr, int lg, int w) {
  lsum += __shfl_xor(lsum, 16, 64);
  lsum += __shfl_xor(lsum, 32, 64);
  float inv = 1.0f / lsum;
  float iv[4];
  #pragma unroll
  for (int r = 0; r < 4; r++) iv[r] = __shfl(inv, lg * 4 + r, 64);
  #pragma unroll
  for (int r = 0; r < 4; r++) {
    int orow = q0 + w * 16 + lg * 4 + r;
    size_t base = (size_t)(b * T_ + orow) * 2048 + (size_t)(g * 4 + h) * 128;
    #pragma unroll
    for (int nd = 0; nd < 8; nd++)
      ob[base + nd * 16 + lr] = f2bf(oacc[nd][r] * iv[r]);
  }
}

// ---------- causal flash attention: dual Q-tiles {31-p, p} share staged K/V ----------
__global__ __launch_bounds__(256, 2) void k_attn(
    const u16* __restrict__ qb, const u16* __restrict__ kb,
    const u16* __restrict__ vtb, u16* __restrict__ ob) {
  __shared__ __align__(16) u16 Ks[2][64 * 128];
  __shared__ __align__(16) u16 Vs[2][128 * 64];
  __shared__ __align__(16) u16 PsA[4][16 * 64];
  __shared__ __align__(16) u16 PsB[4][16 * 64];
  const int head = blockIdx.y;       // ((b*4+g)*4+h)
  const int p = blockIdx.x;          // 0..15
  const int b = head >> 4, g = (head >> 2) & 3, h = head & 3;
  const int tid = threadIdx.x;
  const int w = tid >> 6, lane = tid & 63;
  const int lr = lane & 15, lg = lane >> 4;
  const u16* qh = qb + (size_t)head * (T_ * 128);
  const u16* kh = kb + (size_t)(b * 4 + g) * (T_ * 128);
  const u16* vh = vtb + (size_t)(b * 4 + g) * (128 * T_);

  const int qA = 31 - p, qB = p;     // qB < qA always (p <= 15)
  bf16x8 qfA[4], qfB[4];
  {
    const int rA = qA * 64 + w * 16 + lr;
    const int rB = qB * 64 + w * 16 + lr;
    #pragma unroll
    for (int kk = 0; kk < 4; kk++) {
      qfA[kk] = *(const bf16x8*)&qh[(size_t)rA * 128 + kk * 32 + lg * 8];
      qfB[kk] = *(const bf16x8*)&qh[(size_t)rB * 128 + kk * 32 + lg * 8];
    }
  }
  f32x4 oaccA[8] = {}, oaccB[8] = {};
  float mrunA = -3.0e38f, lsumA = 0.f;
  float mrunB = -3.0e38f, lsumB = 0.f;

  stage_tiles(kh, vh, 0, Ks[0], Vs[0], tid);
  asm volatile("s_waitcnt vmcnt(0)" ::: "memory");
  __builtin_amdgcn_s_barrier();
  asm volatile("" ::: "memory");
  int cur = 0;
  for (int jt = 0; jt <= qA; ++jt) {
    if (jt < qA)
      stage_tiles(kh, vh, (jt + 1) * 64, Ks[cur ^ 1], Vs[cur ^ 1], tid);
    attn_tile(Ks[cur], Vs[cur], PsA[w], qfA, oaccA, mrunA, lsumA, lr, lg, w, jt == qA);
    if (jt <= qB)
      attn_tile(Ks[cur], Vs[cur], PsB[w], qfB, oaccB, mrunB, lsumB, lr, lg, w, jt == qB);
    asm volatile("s_waitcnt vmcnt(0)" ::: "memory");
    __builtin_amdgcn_s_barrier();
    asm volatile("" ::: "memory");
    cur ^= 1;
  }
  attn_epilogue(ob, b, g, h, qA * 64, oaccA, lsumA, lr, lg, w);
  attn_epilogue(ob, b, g, h, qB * 64, oaccB, lsumB, lr, lg, w);
}

// ---------- workspace layout (bytes) ----------
#define OFF_XB    ((size_t)0)          /* 16MB  x bf16 */
#define OFF_WQKVT ((size_t)16777216)   /* 12.6MB  [3072][2048] */
#define OFF_WOT   ((size_t)29360128)   /*  8MB */
#define OFF_ROPE  ((size_t)37748736)   /*  1MB */
#define OFF_QB    ((size_t)38797312)   /* 16MB */
#define OFF_KB    ((size_t)55574528)   /*  4MB */
#define OFF_VTB   ((size_t)59768832)   /*  4MB */
#define OFF_QKVF  ((size_t)63963136)   /* 25.2MB  [4096][3072] */
#define OFF_OB    OFF_QKVF             /* reuse: qkv_bf dead after norm/pack kernels */

extern "C" void kernel_launch(void* const* d_in, const int* in_sizes, int n_in,
                              void* d_out, int out_size, void* d_ws, size_t ws_size,
                              hipStream_t stream) {
  const float* x  = (const float*)d_in[0];
  const float* wq = (const float*)d_in[1];
  const float* wk = (const float*)d_in[2];
  const float* wv = (const float*)d_in[3];
  const float* wo = (const float*)d_in[4];
  const float* gq = (const float*)d_in[5];
  const float* gk = (const float*)d_in[6];
  float* out = (float*)d_out;
  char* ws = (char*)d_ws;

  u16*    xb    = (u16*)(ws + OFF_XB);
  u16*    wqkvt = (u16*)(ws + OFF_WQKVT);
  u16*    wot   = (u16*)(ws + OFF_WOT);
  float2* rope  = (float2*)(ws + OFF_ROPE);
  u16*    qbuf  = (u16*)(ws + OFF_QB);
  u16*    kbuf  = (u16*)(ws + OFF_KB);
  u16*    vtb   = (u16*)(ws + OFF_VTB);
  u16*    qkvf  = (u16*)(ws + OFF_QKVF);
  u16*    obuf  = (u16*)(ws + OFF_OB);

  // 1. conversions
  k_convert<<<8192, 256, 0, stream>>>(x, xb, (MROWS * DM) / 4);
  k_transpose<<<dim3(64, 64), dim3(32, 8), 0, stream>>>(wq, wqkvt, 2048, 2048);
  k_transpose<<<dim3(16, 64), dim3(32, 8), 0, stream>>>(wk, wqkvt + (size_t)2048 * 2048, 2048, 512);
  k_transpose<<<dim3(16, 64), dim3(32, 8), 0, stream>>>(wv, wqkvt + (size_t)2560 * 2048, 2048, 512);
  k_transpose<<<dim3(64, 64), dim3(32, 8), 0, stream>>>(wo, wot, 2048, 2048);
  k_rope_table<<<512, 256, 0, stream>>>(rope);
  // 2. fused QKV projection: [4096][3072]
  k_gemm<u16><<<dim3(24, 32), 256, 0, stream>>>(xb, wqkvt, qkvf, MROWS, 3072, 2048);
  // 3. norm + rope + layout
  k_norm_rope_q<<<16384, 256, 0, stream>>>(qkvf, gq, rope, qbuf);
  k_norm_rope_k<<<4096, 256, 0, stream>>>(qkvf, gk, rope, kbuf);
  k_pack_vt<<<1024, 256, 0, stream>>>(qkvf, vtb);
  // 4. attention: dual Q-tiles per block, uniform compute per block
  k_attn<<<dim3(16, 32), 256, 0, stream>>>(qbuf, kbuf, vtb, obuf);
  // 5. output projection (fp32 out)
  k_gemm<float><<<dim3(16, 32), 256, 0, stream>>>(obuf, wot, out, MROWS, 2048, 2048);
}

// Round 4
// 226.019 us; speedup vs baseline: 1.2530x; 1.2530x over previous
//
#include <hip/hip_runtime.h>
#include <cstdint>

typedef unsigned short u16;
typedef __attribute__((ext_vector_type(8))) __bf16 bf16x8;
typedef __attribute__((ext_vector_type(4))) float f32x4;
typedef __attribute__((ext_vector_type(8))) unsigned short u16x8;

#define DEV __device__ __forceinline__

DEV u16 f2bf(float f) {
  __bf16 b = (__bf16)f;
  return __builtin_bit_cast(u16, b);
}
DEV float bf2f(u16 h) { return __uint_as_float(((unsigned)h) << 16); }
DEV float exp2_fast(float x) { float r; asm("v_exp_f32 %0, %1" : "=v"(r) : "v"(x)); return r; }

typedef __attribute__((address_space(1))) void gvoid_t;
typedef __attribute__((address_space(3))) void lvoid_t;

DEV void gload_lds16(const void* g, void* l) {
  __builtin_amdgcn_global_load_lds((gvoid_t*)(void*)(uintptr_t)g,
                                   (lvoid_t*)l, 16, 0, 0);
}

// ---- problem sizes
#define B_   2
#define T_   2048
#define DM   2048
#define MROWS (B_*T_)   // 4096

// ---------- x f32 -> bf16 ----------
__global__ void k_convert(const float* __restrict__ in, u16* __restrict__ out, int n4) {
  int i = blockIdx.x * blockDim.x + threadIdx.x;
  if (i >= n4) return;
  float4 v = ((const float4*)in)[i];
  ((ushort4*)out)[i] = make_ushort4(f2bf(v.x), f2bf(v.y), f2bf(v.z), f2bf(v.w));
}

// ---------- weight f32 [R][C] -> bf16 [C][R] ----------
__global__ void k_transpose(const float* __restrict__ in, u16* __restrict__ out, int R, int C) {
  __shared__ float tile[32][33];
  int c0 = blockIdx.x * 32, r0 = blockIdx.y * 32;
  int tx = threadIdx.x, ty = threadIdx.y;   // (32, 8)
  #pragma unroll
  for (int j = 0; j < 32; j += 8)
    tile[ty + j][tx] = in[(size_t)(r0 + ty + j) * C + c0 + tx];
  __syncthreads();
  #pragma unroll
  for (int j = 0; j < 32; j += 8)
    out[(size_t)(c0 + ty + j) * R + r0 + tx] = f2bf(tile[tx][ty + j]);
}

// ---------- RoPE cos/sin table [T][64] ----------
__global__ void k_rope_table(float2* __restrict__ tab) {
  int i = blockIdx.x * blockDim.x + threadIdx.x;   // < 2048*64
  int pos = i >> 6, d = i & 63;
  float ang = powf(10000.0f, -(float)d / 64.0f);
  float s, c;
  sincosf((float)pos * ang, &s, &c);
  tab[i] = make_float2(c, s);
}

// ---------- bf16 GEMM: C[M][N] = A[M][K] * BT[N][K]^T ----------
template <typename OutT>
__global__ __launch_bounds__(256) void k_gemm(
    const u16* __restrict__ A, const u16* __restrict__ BT, OutT* __restrict__ C,
    int M, int N, int K) {
  __shared__ u16 As[128 * 64];
  __shared__ u16 Bs[128 * 64];
  const int tid = threadIdx.x;
  const int w = tid >> 6, lane = tid & 63;
  const int lr = lane & 15, lg = lane >> 4;
  const int m0 = blockIdx.y * 128, n0 = blockIdx.x * 128;
  const int wr = w >> 1, wc = w & 1;
  f32x4 acc[4][4] = {};
  for (int k0 = 0; k0 < K; k0 += 64) {
    __syncthreads();
    #pragma unroll
    for (int i = 0; i < 4; i++) {
      int idx = i * 256 + tid;            // 0..1023
      int row = idx >> 3, blk = idx & 7;  // 8x16B blocks per 128B row
      int scol = ((blk ^ (row & 7)) << 3);
      gload_lds16(&A[(size_t)(m0 + row) * K + k0 + scol], &As[(idx & ~63) * 8]);
      gload_lds16(&BT[(size_t)(n0 + row) * K + k0 + scol], &Bs[(idx & ~63) * 8]);
    }
    __syncthreads();
    #pragma unroll
    for (int kk = 0; kk < 2; kk++) {
      bf16x8 af[4], bfr[4];
      #pragma unroll
      for (int m = 0; m < 4; m++) {
        int row = wr * 64 + m * 16 + lr;
        af[m] = *(const bf16x8*)&As[row * 64 + (((kk * 4 + lg) ^ (lr & 7)) << 3)];
      }
      #pragma unroll
      for (int n = 0; n < 4; n++) {
        int row = wc * 64 + n * 16 + lr;
        bfr[n] = *(const bf16x8*)&Bs[row * 64 + (((kk * 4 + lg) ^ (lr & 7)) << 3)];
      }
      #pragma unroll
      for (int m = 0; m < 4; m++)
        #pragma unroll
        for (int n = 0; n < 4; n++)
          acc[m][n] = __builtin_amdgcn_mfma_f32_16x16x32_bf16(af[m], bfr[n], acc[m][n], 0, 0, 0);
    }
  }
  #pragma unroll
  for (int m = 0; m < 4; m++)
    #pragma unroll
    for (int n = 0; n < 4; n++)
      #pragma unroll
      for (int r = 0; r < 4; r++) {
        int row = m0 + wr * 64 + m * 16 + lg * 4 + r;
        int col = n0 + wc * 64 + n * 16 + lr;
        if constexpr (sizeof(OutT) == 2) C[(size_t)row * N + col] = f2bf(acc[m][n][r]);
        else                             C[(size_t)row * N + col] = acc[m][n][r];
      }
}

// ---------- Q: RMSNorm * gq, RoPE, * (D^-0.5 * log2e) ; qkv [bt][3072] -> [b,g,h,t,d] ----------
__global__ void k_norm_rope_q(const u16* __restrict__ qkvf, const float* __restrict__ gq,
                              const float2* __restrict__ tab, u16* __restrict__ qb) {
  int w = threadIdx.x >> 6, lane = threadIdx.x & 63;
  int W = blockIdx.x * 4 + w;               // 0..65535
  int h = W & 3, g = (W >> 2) & 3;
  int bt = W >> 4;
  int t = bt & 2047, b = bt >> 11;
  const u16* row = qkvf + (size_t)bt * 3072 + (size_t)(g * 4 + h) * 128;
  float v0 = bf2f(row[lane]);
  float v1 = bf2f(row[lane + 64]);
  float ss = v0 * v0 + v1 * v1;
  #pragma unroll
  for (int off = 1; off < 64; off <<= 1) ss += __shfl_xor(ss, off, 64);
  float inv = 1.0f / sqrtf(ss * (1.0f / 128.0f) + 1e-6f);
  v0 *= inv * gq[(g * 4 + h) * 128 + lane];
  v1 *= inv * gq[(g * 4 + h) * 128 + 64 + lane];
  float2 cs = tab[t * 64 + lane];
  const float sc = 0.1275174f;    // 128^-0.5 * log2(e), both mult factors folded into q
  float o0 = (v0 * cs.x - v1 * cs.y) * sc;
  float o1 = (v0 * cs.y + v1 * cs.x) * sc;
  u16* orow = qb + ((size_t)(((b * 4 + g) * 4 + h) * 2048 + t)) * 128;
  orow[lane] = f2bf(o0);
  orow[lane + 64] = f2bf(o1);
}

// ---------- K: RMSNorm * gk, RoPE ; qkv [bt][3072] cols 2048..2559 -> [b,g,t,d] ----------
__global__ void k_norm_rope_k(const u16* __restrict__ qkvf, const float* __restrict__ gk,
                              const float2* __restrict__ tab, u16* __restrict__ kb) {
  int w = threadIdx.x >> 6, lane = threadIdx.x & 63;
  int W = blockIdx.x * 4 + w;               // 0..16383
  int g = W & 3;
  int bt = W >> 2;
  int t = bt & 2047, b = bt >> 11;
  const u16* row = qkvf + (size_t)bt * 3072 + 2048 + (size_t)g * 128;
  float v0 = bf2f(row[lane]);
  float v1 = bf2f(row[lane + 64]);
  float ss = v0 * v0 + v1 * v1;
  #pragma unroll
  for (int off = 1; off < 64; off <<= 1) ss += __shfl_xor(ss, off, 64);
  float inv = 1.0f / sqrtf(ss * (1.0f / 128.0f) + 1e-6f);
  v0 *= inv * gk[g * 128 + lane];
  v1 *= inv * gk[g * 128 + 64 + lane];
  float2 cs = tab[t * 64 + lane];
  float o0 = v0 * cs.x - v1 * cs.y;
  float o1 = v0 * cs.y + v1 * cs.x;
  u16* orow = kb + ((size_t)((b * 4 + g) * 2048 + t)) * 128;
  orow[lane] = f2bf(o0);
  orow[lane + 64] = f2bf(o1);
}

// ---------- V: qkv [bt][3072] cols 2560..3071 -> VT [b,g,d,t] ----------
__global__ void k_pack_vt(const u16* __restrict__ qkvf, u16* __restrict__ vt) {
  int w = threadIdx.x >> 6, lane = threadIdx.x & 63;
  int W = blockIdx.x * 4 + w;               // 0..4095
  int t8 = W & 255, dh = (W >> 8) & 1, bg = W >> 9;
  int b = bg >> 2, g = bg & 3;
  int t0 = t8 * 8;
  int d = dh * 64 + lane;
  u16x8 pack;
  #pragma unroll
  for (int j = 0; j < 8; j++)
    pack[j] = qkvf[(size_t)(b * 2048 + t0 + j) * 3072 + 2560 + g * 128 + d];
  *(u16x8*)&vt[((size_t)(bg * 128 + d)) * 2048 + t0] = pack;
}

// ---------- staging: K tile [64][128] + VT tile [128][64], pre-swizzled source ----------
DEV void stage_tiles(const u16* kh, const u16* vh, int j0, u16* Kbuf, u16* Vbuf, int tid) {
  #pragma unroll
  for (int i = 0; i < 4; i++) {
    int idx = i * 256 + tid;
    int row = idx >> 4, blk = idx & 15;   // 16x16B blocks per 256B K row
    gload_lds16(&kh[(size_t)(j0 + row) * 128 + ((blk ^ (row & 7)) << 3)],
                &Kbuf[(idx & ~63) * 8]);
  }
  #pragma unroll
  for (int i = 0; i < 4; i++) {
    int idx = i * 256 + tid;
    int row = idx >> 3, blk = idx & 7;    // 8x16B blocks per 128B VT row
    gload_lds16(&vh[(size_t)row * T_ + j0 + ((blk ^ (row & 7)) << 3)],
                &Vbuf[(idx & ~63) * 8]);
  }
}

// ---------- one q-tile's QK^T + online softmax (exp2 domain, defer-max) + PV ----------
DEV void attn_tile(const u16* __restrict__ Kc, const u16* __restrict__ Vc,
                   u16* __restrict__ Psw, const bf16x8* qf, f32x4* oacc,
                   float& mrun, float& lsum,
                   int lr, int lg, int w, bool diag) {
  // S^T = K . Q^T : col = q (lr), row = kv (c*16 + lg*4 + r)
  f32x4 s[4] = {};
  #pragma unroll
  for (int kk = 0; kk < 4; kk++) {
    #pragma unroll
    for (int c = 0; c < 4; c++) {
      const int kvr = c * 16 + lr;
      bf16x8 kf = *(const bf16x8*)&Kc[kvr * 128 + (((kk * 4 + lg) ^ (kvr & 7)) << 3)];
      s[c] = __builtin_amdgcn_mfma_f32_16x16x32_bf16(kf, qf[kk], s[c], 0, 0, 0);
    }
  }
  if (diag) {
    #pragma unroll
    for (int c = 0; c < 4; c++)
      #pragma unroll
      for (int r = 0; r < 4; r++)
        if (c * 16 + lg * 4 + r > w * 16 + lr) s[c][r] = -1.0e30f;
  }
  float mx = s[0][0];
  #pragma unroll
  for (int c = 0; c < 4; c++)
    #pragma unroll
    for (int r = 0; r < 4; r++) mx = fmaxf(mx, s[c][r]);
  mx = fmaxf(mx, __shfl_xor(mx, 16, 64));
  mx = fmaxf(mx, __shfl_xor(mx, 32, 64));
  // defer-max: only rescale when tile max grew past mrun + 11 (log2 units; P <= 2^11)
  if (!__all(mx <= mrun + 11.0f)) {
    float mnew = fmaxf(mrun, mx);
    float corr = exp2_fast(mrun - mnew);
    mrun = mnew;
    lsum *= corr;
    float cr[4];
    #pragma unroll
    for (int r = 0; r < 4; r++) cr[r] = __shfl(corr, lg * 4 + r, 64);
    #pragma unroll
    for (int nd = 0; nd < 8; nd++) {
      oacc[nd][0] *= cr[0]; oacc[nd][1] *= cr[1];
      oacc[nd][2] *= cr[2]; oacc[nd][3] *= cr[3];
    }
  }
  float rs = 0.f;
  #pragma unroll
  for (int c = 0; c < 4; c++)
    #pragma unroll
    for (int r = 0; r < 4; r++) {
      float pv = exp2_fast(s[c][r] - mrun);
      s[c][r] = pv;
      rs += pv;
    }
  lsum += rs;                 // per-lane partial; cross-lane reduce deferred to epilogue
  // P store: P[q=lr][kv quad c*16+lg*4], b64, XOR-swizzled 8B blocks
  #pragma unroll
  for (int c = 0; c < 4; c++) {
    ushort4 q4 = make_ushort4(f2bf(s[c][0]), f2bf(s[c][1]), f2bf(s[c][2]), f2bf(s[c][3]));
    int blk8 = (c * 4 + lg) ^ ((lr & 7) << 1);
    *(ushort4*)&Psw[lr * 64 + blk8 * 4] = q4;
  }
  // O += P V
  #pragma unroll
  for (int ks = 0; ks < 2; ks++) {
    bf16x8 pf = *(const bf16x8*)&Psw[lr * 64 +
                 (((2 * (ks * 4 + lg)) ^ ((lr & 7) << 1)) << 2)];
    #pragma unroll
    for (int nd = 0; nd < 8; nd++) {
      const int d = nd * 16 + lr;
      bf16x8 vf = *(const bf16x8*)&Vc[d * 64 + (((ks * 4 + lg) ^ (d & 7)) << 3)];
      oacc[nd] = __builtin_amdgcn_mfma_f32_16x16x32_bf16(pf, vf, oacc[nd], 0, 0, 0);
    }
  }
}

DEV void attn_epilogue(u16* __restrict__ ob, int b, int g, int h, int q0,
                       const f32x4* oacc, float lsum, int lr, int lg, int w) {
  lsum += __shfl_xor(lsum, 16, 64);
  lsum += __shfl_xor(lsum, 32, 64);
  float inv = 1.0f / lsum;
  float iv[4];
  #pragma unroll
  for (int r = 0; r < 4; r++) iv[r] = __shfl(inv, lg * 4 + r, 64);
  #pragma unroll
  for (int r = 0; r < 4; r++) {
    int orow = q0 + w * 16 + lg * 4 + r;
    size_t base = (size_t)(b * T_ + orow) * 2048 + (size_t)(g * 4 + h) * 128;
    #pragma unroll
    for (int nd = 0; nd < 8; nd++)
      ob[base + nd * 16 + lr] = f2bf(oacc[nd][r] * iv[r]);
  }
}

// ---------- causal flash attention: paired Q-tiles {31-p, p} run sequentially ----------
// Uniform work per block (34 tile-iters), single live accumulator set (no spills).
__global__ __launch_bounds__(256) void k_attn(
    const u16* __restrict__ qb, const u16* __restrict__ kb,
    const u16* __restrict__ vtb, u16* __restrict__ ob) {
  __shared__ __align__(16) u16 Ks[2][64 * 128];
  __shared__ __align__(16) u16 Vs[2][128 * 64];
  __shared__ __align__(16) u16 Ps[4][16 * 64];
  const int head = blockIdx.y;       // ((b*4+g)*4+h)
  const int b = head >> 4, g = (head >> 2) & 3, h = head & 3;
  const int tid = threadIdx.x;
  const int w = tid >> 6, lane = tid & 63;
  const int lr = lane & 15, lg = lane >> 4;
  const u16* qh = qb + (size_t)head * (T_ * 128);
  const u16* kh = kb + (size_t)(b * 4 + g) * (T_ * 128);
  const u16* vh = vtb + (size_t)(b * 4 + g) * (128 * T_);

  #pragma unroll 1
  for (int half = 0; half < 2; ++half) {
    const int qblk = half ? (int)blockIdx.x : 31 - (int)blockIdx.x;  // big tile first
    const int q0 = qblk * 64;
    bf16x8 qf[4];
    const int qrow = q0 + w * 16 + lr;
    #pragma unroll
    for (int kk = 0; kk < 4; kk++)
      qf[kk] = *(const bf16x8*)&qh[(size_t)qrow * 128 + kk * 32 + lg * 8];

    f32x4 oacc[8] = {};
    float mrun = -3.0e38f, lsum = 0.f;

    stage_tiles(kh, vh, 0, Ks[0], Vs[0], tid);
    asm volatile("s_waitcnt vmcnt(0)" ::: "memory");
    __builtin_amdgcn_s_barrier();
    asm volatile("" ::: "memory");
    int cur = 0;
    for (int jt = 0; jt <= qblk; ++jt) {
      if (jt < qblk)
        stage_tiles(kh, vh, (jt + 1) * 64, Ks[cur ^ 1], Vs[cur ^ 1], tid);
      attn_tile(Ks[cur], Vs[cur], Ps[w], qf, oacc, mrun, lsum, lr, lg, w, jt == qblk);
      asm volatile("s_waitcnt vmcnt(0)" ::: "memory");
      __builtin_amdgcn_s_barrier();
      asm volatile("" ::: "memory");
      cur ^= 1;
    }
    attn_epilogue(ob, b, g, h, q0, oacc, lsum, lr, lg, w);
  }
}

// ---------- workspace layout (bytes) ----------
#define OFF_XB    ((size_t)0)          /* 16MB  x bf16 */
#define OFF_WQKVT ((size_t)16777216)   /* 12.6MB  [3072][2048] */
#define OFF_WOT   ((size_t)29360128)   /*  8MB */
#define OFF_ROPE  ((size_t)37748736)   /*  1MB */
#define OFF_QB    ((size_t)38797312)   /* 16MB */
#define OFF_KB    ((size_t)55574528)   /*  4MB */
#define OFF_VTB   ((size_t)59768832)   /*  4MB */
#define OFF_QKVF  ((size_t)63963136)   /* 25.2MB  [4096][3072] */
#define OFF_OB    OFF_QKVF             /* reuse: qkv_bf dead after norm/pack kernels */

extern "C" void kernel_launch(void* const* d_in, const int* in_sizes, int n_in,
                              void* d_out, int out_size, void* d_ws, size_t ws_size,
                              hipStream_t stream) {
  const float* x  = (const float*)d_in[0];
  const float* wq = (const float*)d_in[1];
  const float* wk = (const float*)d_in[2];
  const float* wv = (const float*)d_in[3];
  const float* wo = (const float*)d_in[4];
  const float* gq = (const float*)d_in[5];
  const float* gk = (const float*)d_in[6];
  float* out = (float*)d_out;
  char* ws = (char*)d_ws;

  u16*    xb    = (u16*)(ws + OFF_XB);
  u16*    wqkvt = (u16*)(ws + OFF_WQKVT);
  u16*    wot   = (u16*)(ws + OFF_WOT);
  float2* rope  = (float2*)(ws + OFF_ROPE);
  u16*    qbuf  = (u16*)(ws + OFF_QB);
  u16*    kbuf  = (u16*)(ws + OFF_KB);
  u16*    vtb   = (u16*)(ws + OFF_VTB);
  u16*    qkvf  = (u16*)(ws + OFF_QKVF);
  u16*    obuf  = (u16*)(ws + OFF_OB);

  // 1. conversions
  k_convert<<<8192, 256, 0, stream>>>(x, xb, (MROWS * DM) / 4);
  k_transpose<<<dim3(64, 64), dim3(32, 8), 0, stream>>>(wq, wqkvt, 2048, 2048);
  k_transpose<<<dim3(16, 64), dim3(32, 8), 0, stream>>>(wk, wqkvt + (size_t)2048 * 2048, 2048, 512);
  k_transpose<<<dim3(16, 64), dim3(32, 8), 0, stream>>>(wv, wqkvt + (size_t)2560 * 2048, 2048, 512);
  k_transpose<<<dim3(64, 64), dim3(32, 8), 0, stream>>>(wo, wot, 2048, 2048);
  k_rope_table<<<512, 256, 0, stream>>>(rope);
  // 2. fused QKV projection: [4096][3072]
  k_gemm<u16><<<dim3(24, 32), 256, 0, stream>>>(xb, wqkvt, qkvf, MROWS, 3072, 2048);
  // 3. norm + rope + layout
  k_norm_rope_q<<<16384, 256, 0, stream>>>(qkvf, gq, rope, qbuf);
  k_norm_rope_k<<<4096, 256, 0, stream>>>(qkvf, gk, rope, kbuf);
  k_pack_vt<<<1024, 256, 0, stream>>>(qkvf, vtb);
  // 4. attention: paired Q-tiles {31-p, p} sequential, uniform work per block
  k_attn<<<dim3(16, 32), 256, 0, stream>>>(qbuf, kbuf, vtb, obuf);
  // 5. output projection (fp32 out)
  k_gemm<float><<<dim3(16, 32), 256, 0, stream>>>(obuf, wot, out, MROWS, 2048, 2048);
}